// Round 2
// baseline (344.981 us; speedup 1.0000x reference)
//
#include <hip/hip_runtime.h>

#define SEQ 512
#define TAGS 64
#define NB 128
#define START_TAG 62
#define STOP_TAG 63

__device__ __forceinline__ float readlane_f(float v, int lane) {
    return __int_as_float(__builtin_amdgcn_readlane(__float_as_int(v), lane));
}

// Partial max/argmax over prev-tags i in [16W, 16W+16), reference association
// order: val = (f[j] + trans[i][j]) + p[i]; strict > ascending i = first-occurrence.
template<int W>
__device__ __forceinline__ void partial_max(float pv, const float (&tw)[16], float fcur,
                                            float& best, int& bidx) {
#pragma unroll
    for (int k = 0; k < 16; ++k) {
        float tmp = fcur + tw[k];                    // f[j] + trans[i][j]
        float pi  = readlane_f(pv, W * 16 + k);      // p[i] broadcast (literal lane)
        float val = tmp + pi;
        if (val > best) { best = val; bidx = W * 16 + k; }
    }
}

__global__ __launch_bounds__(256) void crf_viterbi(const float* __restrict__ feats,
                                                   const void* __restrict__ maskp,
                                                   const float* __restrict__ trans,
                                                   int* __restrict__ out) {
    __shared__ float pval[2][4][TAGS];
    __shared__ int   pidx[2][4][TAGS];
    __shared__ unsigned char bp[SEQ * TAGS];   // backpointers, 32 KB

    const int b    = blockIdx.x;
    const int tid  = threadIdx.x;
    const int lane = tid & 63;
    const int w    = tid >> 6;

    // ---- sequence length from mask (dtype auto-detect; mask is a prefix of 1s) ----
    int lsum = 0;
    {
        const int* mi = (const int*)maskp;
        int w0 = mi[0];                          // first entry is always "true"
        if (w0 == 1) {                           // int32 0/1
            const int* row = mi + b * SEQ;
#pragma unroll
            for (int r = 0; r < 8; ++r) lsum += row[lane + 64 * r];
        } else if (w0 == 0x01010101) {           // bool bytes
            const int* row = (const int*)((const unsigned char*)maskp + b * SEQ);
#pragma unroll
            for (int r = 0; r < 2; ++r) {
                int v = row[lane + 64 * r];
                lsum += (v & 1) + ((v >> 8) & 1) + ((v >> 16) & 1) + ((v >> 24) & 1);
            }
        } else {                                 // float 1.0/0.0
            const float* row = (const float*)maskp + b * SEQ;
            float fa = 0.f;
#pragma unroll
            for (int r = 0; r < 8; ++r) fa += row[lane + 64 * r];
            lsum = (int)fa;
        }
#pragma unroll
        for (int off = 32; off >= 1; off >>= 1) lsum += __shfl_xor(lsum, off);
    }
    const int L = __builtin_amdgcn_readfirstlane(lsum);

    // ---- preload transition slices ----
    float tw[16];                                // trans[i][j] for this wave's 16 i's
#pragma unroll
    for (int k = 0; k < 16; ++k) tw[k] = trans[(w * 16 + k) * TAGS + lane];
    const float tstop  = trans[lane * TAGS + STOP_TAG];   // trans[j][STOP]
    const float tstart = trans[START_TAG * TAGS + lane];  // trans[START][j]

    const float* frow = feats + (size_t)b * SEQ * TAGS;
    float pv = frow[lane] + tstart;              // partition at t=0; lane j holds p[j]

    float fnext = frow[TAGS + lane];             // prefetch feats row t=1 (L >= 128)
    int buf = 0;
    for (int t = 1; t < L; ++t) {
        float fcur = fnext;
        int tn = (t + 1 < SEQ) ? (t + 1) : t;    // safe prefetch of next row
        fnext = frow[tn * TAGS + lane];

        float best = -3.4e38f; int bidx = 0;
        switch (w) {                             // uniform branch -> literal readlanes
            case 0:  partial_max<0>(pv, tw, fcur, best, bidx); break;
            case 1:  partial_max<1>(pv, tw, fcur, best, bidx); break;
            case 2:  partial_max<2>(pv, tw, fcur, best, bidx); break;
            default: partial_max<3>(pv, tw, fcur, best, bidx); break;
        }
        pval[buf][w][lane] = best;
        pidx[buf][w][lane] = bidx;
        __syncthreads();                         // one barrier/step (double-buffered)
        float b0 = pval[buf][0][lane]; int i0 = pidx[buf][0][lane];
        float b1 = pval[buf][1][lane]; int i1 = pidx[buf][1][lane];
        float b2 = pval[buf][2][lane]; int i2 = pidx[buf][2][lane];
        float b3 = pval[buf][3][lane]; int i3 = pidx[buf][3][lane];
        float bb = b0; int bi = i0;              // strict > ascending-wave: first-idx ties
        if (b1 > bb) { bb = b1; bi = i1; }
        if (b2 > bb) { bb = b2; bi = i2; }
        if (b3 > bb) { bb = b3; bi = i3; }
        if (w == 0) bp[t * TAGS + lane] = (unsigned char)bi;
        pv = bb;                                 // value already includes feats[t][j]
        buf ^= 1;
    }

    // ---- pointer0 = argmax_i( p[i] + trans[i][STOP] ), first-occurrence ties ----
    float v = pv + tstop; int idx = lane;
#pragma unroll
    for (int off = 32; off >= 1; off >>= 1) {
        float ov = __shfl_xor(v, off);
        int   oi = __shfl_xor(idx, off);
        bool take = (ov > v) || (ov == v && oi < idx);
        v   = take ? ov : v;
        idx = take ? oi : idx;
    }
    const int ptr0 = __builtin_amdgcn_readfirstlane(idx);

    int* outrow = out + b * SEQ;
    // tail: decode[L-1] = ptr0, decode[S-1] = ptr0, (L-1, S-1) exclusive = 0
    for (int t = tid; t < SEQ; t += 256) {
        if (t == L - 1 || t == SEQ - 1) outrow[t] = ptr0;
        else if (t > L - 1)             outrow[t] = 0;
    }

    // ---- backtrace (wave 0 only; bp rows were written by wave 0, wave-coherent) ----
    if (w == 0) {
        int ptr = ptr0;
        int t = L - 2;
        while (t >= 7) {
            // prefetch 8 bp rows into lanes (independent of the chase)
            int r0 = bp[(t + 1) * TAGS + lane];
            int r1 = bp[(t    ) * TAGS + lane];
            int r2 = bp[(t - 1) * TAGS + lane];
            int r3 = bp[(t - 2) * TAGS + lane];
            int r4 = bp[(t - 3) * TAGS + lane];
            int r5 = bp[(t - 4) * TAGS + lane];
            int r6 = bp[(t - 5) * TAGS + lane];
            int r7 = bp[(t - 6) * TAGS + lane];
            // dependent chain is cheap v_readlane with uniform (SGPR) index
            ptr = __builtin_amdgcn_readlane(r0, ptr); if (lane == 0) outrow[t    ] = ptr;
            ptr = __builtin_amdgcn_readlane(r1, ptr); if (lane == 0) outrow[t - 1] = ptr;
            ptr = __builtin_amdgcn_readlane(r2, ptr); if (lane == 0) outrow[t - 2] = ptr;
            ptr = __builtin_amdgcn_readlane(r3, ptr); if (lane == 0) outrow[t - 3] = ptr;
            ptr = __builtin_amdgcn_readlane(r4, ptr); if (lane == 0) outrow[t - 4] = ptr;
            ptr = __builtin_amdgcn_readlane(r5, ptr); if (lane == 0) outrow[t - 5] = ptr;
            ptr = __builtin_amdgcn_readlane(r6, ptr); if (lane == 0) outrow[t - 6] = ptr;
            ptr = __builtin_amdgcn_readlane(r7, ptr); if (lane == 0) outrow[t - 7] = ptr;
            t -= 8;
        }
        while (t >= 0) {
            ptr = bp[(t + 1) * TAGS + ptr];      // uniform-address LDS broadcast
            if (lane == 0) outrow[t] = ptr;
            t--;
        }
    }
}

extern "C" void kernel_launch(void* const* d_in, const int* in_sizes, int n_in,
                              void* d_out, int out_size, void* d_ws, size_t ws_size,
                              hipStream_t stream) {
    const float* feats = (const float*)d_in[0];
    const void*  maskp = d_in[1];
    // d_in[2] = tags (unused by the reference decode)
    const float* trans = (const float*)d_in[3];
    int* out = (int*)d_out;
    crf_viterbi<<<NB, 256, 0, stream>>>(feats, maskp, trans, out);
}